// Round 17
// baseline (196.387 us; speedup 1.0000x reference)
//
#include <hip/hip_runtime.h>
#include <math.h>

typedef __attribute__((ext_vector_type(8))) short short8;
typedef __attribute__((ext_vector_type(4))) float f32x4;
typedef __attribute__((ext_vector_type(16))) float f32x16;

#define SW7b(r) (((r) & 7) << 4)
#define SW3b(r) (((r) & 3) << 4)
#define K15(r) (((r) & 15) << 4)

static __device__ __forceinline__ unsigned short f2b(float f){
  unsigned u = __float_as_uint(f);
  u = (u + 0x7FFFu + ((u >> 16) & 1u)) >> 16;
  return (unsigned short)u;
}
static __device__ __forceinline__ float b2f(unsigned short u){
  return __uint_as_float(((unsigned)u) << 16);
}
static __device__ __forceinline__ unsigned pk2(float a, float b){
  unsigned r;
  asm("v_cvt_pk_bf16_f32 %0, %1, %2" : "=v"(r) : "v"(a), "v"(b));
  return r;
}
static __device__ __forceinline__ void gl16(const void* g, void* l) {
  __builtin_amdgcn_global_load_lds(
      (const __attribute__((address_space(1))) void*)g,
      (__attribute__((address_space(3))) void*)l, 16, 0, 0);
}

// ---------------- weight/matrix prep ----------------------------------------------
// k_fu matrices now PLAIN row-major (global in-loop reads): DFTf[160][128],
// fuwb[256][256], IDFTf[128][192], w2b[256][128]. k_conv1/k_lfu layouts unchanged.
__global__ void k_wt(const float* __restrict__ w1, const float* __restrict__ fu_w,
                     const float* __restrict__ lfu_w, const float* __restrict__ w2,
                     const float* __restrict__ g1, const float* __restrict__ b1,
                     const float* __restrict__ m1, const float* __restrict__ v1,
                     const float* __restrict__ fg, const float* __restrict__ fb,
                     const float* __restrict__ fm, const float* __restrict__ fv,
                     const float* __restrict__ lg_, const float* __restrict__ lb_,
                     const float* __restrict__ lm_, const float* __restrict__ lv_,
                     unsigned short* __restrict__ w1b, unsigned short* __restrict__ fuwb,
                     unsigned short* __restrict__ lfuwb, unsigned short* __restrict__ w2b,
                     unsigned short* __restrict__ DFTf, unsigned short* __restrict__ IDFTf,
                     unsigned short* __restrict__ DFTl, unsigned short* __restrict__ IDFTl,
                     float* __restrict__ sc1, float* __restrict__ sh1,
                     float* __restrict__ scF, float* __restrict__ shF,
                     float* __restrict__ scL, float* __restrict__ shL) {
  int t = blockIdx.x * 256 + threadIdx.x;
  const float TPI = 6.283185307179586f;
  if (t < 32768) {
    { int co = t >> 8, k = t & 255; w1b[co * 256 + (k ^ ((co & 7) << 3))] = f2b(w1[t]); }
    w2b[t] = f2b(w2[t]);                 // plain [co2][128]
  }
  if (t < 65536) {
    int co = t >> 8, k = t & 255;
    fuwb[t] = f2b(fu_w[t]);              // plain [co][256]
    lfuwb[co * 256 + (k ^ ((co & 7) << 3))] = f2b(lfu_w[t]);
  }
  if (t < 20480) {                      // DFTf[160][128] plain
    int m = t >> 7, w = t & 127; float v = 0.f;
    if (m < 130) {
      int wf = m >> 1; int ph = (wf * w) & 127;
      float ang = TPI * (float)ph / 128.f;
      v = ((m & 1) ? -sinf(ang) : cosf(ang)) * 0.08838834764831845f;
    }
    DFTf[t] = f2b(v);
  }
  if (t < 24576) {                      // IDFTf[128][192] plain
    int m = t / 192, k2 = t % 192; float v = 0.f;
    if (k2 < 130) {
      int wf = k2 >> 1; float a = (wf == 0 || wf == 64) ? 1.f : 2.f;
      int ph = (wf * m) & 127;
      float ang = TPI * (float)ph / 128.f;
      v = ((k2 & 1) ? -a * sinf(ang) : a * cosf(ang)) * 0.08838834764831845f;
    }
    IDFTf[m * 192 + k2] = f2b(v);
  }
  if (t < 5120) {                       // DFTl[80][64], key m&7 (k_lfu unchanged)
    int m = t >> 6, w = t & 63; float v = 0.f;
    if (m < 66) {
      int wf = m >> 1; int ph = (wf * w) & 63;
      float ang = TPI * (float)ph / 64.f;
      v = ((m & 1) ? -sinf(ang) : cosf(ang)) * 0.125f;
    }
    DFTl[m * 64 + (w ^ ((m & 7) << 3))] = f2b(v);
  }
  if (t < 6144) {                       // IDFTl[64][96], key m&3
    int m = t / 96, k2 = t % 96; float v = 0.f;
    if (k2 < 66) {
      int wf = k2 >> 1; float a = (wf == 0 || wf == 32) ? 1.f : 2.f;
      int ph = (wf * m) & 63;
      float ang = TPI * (float)ph / 64.f;
      v = ((k2 & 1) ? -a * sinf(ang) : a * cosf(ang)) * 0.125f;
    }
    IDFTl[m * 96 + (k2 ^ ((m & 3) << 3))] = f2b(v);
  }
  if (t < 128) { float s = g1[t] * rsqrtf(v1[t] + 1e-3f); sc1[t] = s; sh1[t] = b1[t] - m1[t] * s; }
  if (t < 256) { float s = fg[t] * rsqrtf(fv[t] + 1e-3f); scF[t] = s; shF[t] = fb[t] - fm[t] * s; }
  if (t < 256) { float s = lg_[t] * rsqrtf(lv_[t] + 1e-3f); scL[t] = s; shL[t] = lb_[t] - lm_[t] * s; }
}

// ------------- conv1: unchanged (R16) ---------------------------------------------
__global__ __launch_bounds__(512) void k_conv1(const unsigned short* __restrict__ A,
                                               const float* __restrict__ x,
                                               unsigned short* __restrict__ X1c,
                                               const float* __restrict__ scp,
                                               const float* __restrict__ shp) {
  __shared__ __align__(16) char A_s[128 * 512];
  __shared__ __align__(16) char B_s[2][32768];
  int t = threadIdx.x; int wid = t >> 6, l = t & 63;
  int wm = wid >> 2, wn = wid & 3;
  int m0 = wm * 64, n0 = wn * 64;
  int lr = l & 15, lg = l >> 4;
  size_t nh0 = (size_t)blockIdx.x * 2;
  const char* Ab = (const char*)A;
  const char* xrow = (const char*)(x + nh0 * 32768);
  #pragma unroll
  for (int i = 0; i < 8; i++) { int g = i * 512 + t; gl16(Ab + g * 16, A_s + g * 16); }
  #pragma unroll
  for (int i = 0; i < 4; i++) {
    int g = i * 512 + t; int w = g >> 3, o = g & 7;
    gl16(xrow + (size_t)w * 1024 + ((o * 16) ^ SW7b(w)), B_s[0] + g * 16);
  }
  f32x4 acc[4][4];
  #pragma unroll
  for (int mt = 0; mt < 4; mt++)
    #pragma unroll
    for (int nt = 0; nt < 4; nt++) acc[mt][nt] = (f32x4){0.f, 0.f, 0.f, 0.f};
  __syncthreads();
  for (int it = 0; it < 8; it++) {
    int kk = it * 32;
    if (it < 7) {
      #pragma unroll
      for (int i = 0; i < 4; i++) {
        int g = i * 512 + t; int w = g >> 3, o = g & 7;
        gl16(xrow + (size_t)w * 1024 + (kk + 32) * 4 + ((o * 16) ^ SW7b(w)),
             B_s[(it + 1) & 1] + g * 16);
      }
    }
    const char* Bc = B_s[it & 1];
    short8 af[4], bf[4];
    #pragma unroll
    for (int mt = 0; mt < 4; mt++) {
      int m = m0 + 16 * mt + lr;
      af[mt] = *(const short8*)(A_s + m * 512 + ((kk * 2 + lg * 16) ^ SW7b(m)));
    }
    #pragma unroll
    for (int nt = 0; nt < 4; nt++) {
      int w = n0 + 16 * nt + lr;
      float4 f0 = *(const float4*)(Bc + w * 128 + ((lg * 32) ^ SW7b(w)));
      float4 f1 = *(const float4*)(Bc + w * 128 + ((lg * 32 + 16) ^ SW7b(w)));
      short8 bb;
      bb[0] = (short)f2b(f0.x); bb[1] = (short)f2b(f0.y);
      bb[2] = (short)f2b(f0.z); bb[3] = (short)f2b(f0.w);
      bb[4] = (short)f2b(f1.x); bb[5] = (short)f2b(f1.y);
      bb[6] = (short)f2b(f1.z); bb[7] = (short)f2b(f1.w);
      bf[nt] = bb;
    }
    #pragma unroll
    for (int mt = 0; mt < 4; mt++)
      #pragma unroll
      for (int nt = 0; nt < 4; nt++)
        acc[mt][nt] = __builtin_amdgcn_mfma_f32_16x16x32_bf16(af[mt], bf[nt], acc[mt][nt], 0, 0, 0);
    __syncthreads();
  }
  #pragma unroll
  for (int nt = 0; nt < 4; nt++) {
    int wcol = n0 + 16 * nt + lr;
    char* xout = (char*)X1c + (nh0 + (wcol >> 7)) * 32768;
    int w = wcol & 127;
    #pragma unroll
    for (int mt = 0; mt < 4; mt++) {
      int rb = m0 + 16 * mt + lg * 4;
      float4 s4 = *(const float4*)&scp[rb];
      float4 h4 = *(const float4*)&shp[rb];
      f32x4 v = acc[mt][nt];
      *(unsigned short*)(xout + (rb + 0) * 256 + ((w * 2) ^ K15(rb + 0))) = f2b(fmaxf(v[0] * s4.x + h4.x, 0.f));
      *(unsigned short*)(xout + (rb + 1) * 256 + ((w * 2) ^ K15(rb + 1))) = f2b(fmaxf(v[1] * s4.y + h4.y, 0.f));
      *(unsigned short*)(xout + (rb + 2) * 256 + ((w * 2) ^ K15(rb + 2))) = f2b(fmaxf(v[2] * s4.z + h4.z, 0.f));
      *(unsigned short*)(xout + (rb + 3) * 256 + ((w * 2) ^ K15(rb + 3))) = f2b(fmaxf(v[3] * s4.w + h4.w, 0.f));
    }
  }
}

// ------------- fused local FU: unchanged (R16) ------------------------------------
__global__ __launch_bounds__(256) void k_lfu(const unsigned short* __restrict__ DFTm,
                                             const unsigned short* __restrict__ lfuw,
                                             const unsigned short* __restrict__ IDFTm,
                                             const unsigned short* __restrict__ X1c,
                                             const float* __restrict__ scp,
                                             const float* __restrict__ shp,
                                             unsigned short* __restrict__ XSO) {
  __shared__ __align__(16) char SH[81920];
  char* M   = SH;
  char* S0  = SH + 16384;
  char* FFl = SH + 32768;
  char* Yl  = SH + 57344;
  int t = threadIdx.x, wid = t >> 6, l = t & 63, lr = l & 15, lg = l >> 4;
  int b = blockIdx.x; int n = b >> 6, h2 = b & 63;
  {
    #pragma unroll
    for (int i = 0; i < 3; i++) { int g = i * 256 + t; if (g < 640) gl16((const char*)DFTm + g * 16, M + g * 16); }
    #pragma unroll
    for (int i = 0; i < 4; i++) { int g = i * 256 + t; gl16((const char*)lfuw + g * 16, S0 + g * 16); }
    #pragma unroll
    for (int i = 0; i < 8; i++) {
      int u = i * 256 + t;
      if (u < 1920) *(unsigned*)(FFl + 33 * 512 + u * 4) = 0u;
    }
  }
  __syncthreads();
  {
    short8 bfp[2][2];
    #pragma unroll
    for (int nt = 0; nt < 2; nt++) {
      int c2 = wid * 32 + 16 * nt + lr;
      int c0 = c2 & 31, hb = (c2 >> 5) & 1, wbq = (c2 >> 6) & 1;
      int half = wbq ^ ((c0 >> 3) & 1);
      const char* base = (const char*)X1c +
          ((size_t)(n * 128 + hb * 64 + h2) * 128 + c0) * 256 + half * 128;
      #pragma unroll
      for (int ki = 0; ki < 2; ki++) {
        int kb = ki * 64 + lg * 16;
        bfp[nt][ki] = *(const short8*)(base + (kb ^ SW7b(c2)));
      }
    }
    f32x4 acc[5][2];
    #pragma unroll
    for (int mt = 0; mt < 5; mt++) { acc[mt][0] = (f32x4){0,0,0,0}; acc[mt][1] = (f32x4){0,0,0,0}; }
    #pragma unroll
    for (int ki = 0; ki < 2; ki++) {
      int kb = ki * 64 + lg * 16;
      #pragma unroll
      for (int mt = 0; mt < 5; mt++) {
        int m = 16 * mt + lr;
        short8 af = *(const short8*)(M + m * 128 + (kb ^ SW7b(m)));
        #pragma unroll
        for (int nt = 0; nt < 2; nt++)
          acc[mt][nt] = __builtin_amdgcn_mfma_f32_16x16x32_bf16(af, bfp[nt][ki], acc[mt][nt], 0, 0, 0);
      }
    }
    #pragma unroll
    for (int nt = 0; nt < 2; nt++) {
      int c2 = wid * 32 + 16 * nt + lr;
      #pragma unroll
      for (int mt = 0; mt < 5; mt++) {
        int rb = 16 * mt + lg * 4;
        int wf0 = rb >> 1;
        f32x4 v = acc[mt][nt];
        if (wf0 < 33) {
          unsigned pk = (unsigned)f2b(v[0]) | ((unsigned)f2b(v[1]) << 16);
          *(unsigned*)(FFl + wf0 * 512 + ((4 * c2) ^ SW7b(wf0))) = pk;
        }
        if (wf0 + 1 < 33) {
          unsigned pk = (unsigned)f2b(v[2]) | ((unsigned)f2b(v[3]) << 16);
          *(unsigned*)(FFl + (wf0 + 1) * 512 + ((4 * c2) ^ SW7b(wf0 + 1))) = pk;
        }
      }
    }
  }
  __syncthreads();
  int wm2 = wid >> 1, wn2 = wid & 1;
  for (int ch = 0; ch < 8; ch++) {
    char* Mc = (ch & 1) ? M : S0;
    char* Mn = (ch & 1) ? S0 : M;
    if (ch < 7) {
      #pragma unroll
      for (int i = 0; i < 4; i++) {
        int g = i * 256 + t;
        gl16((const char*)lfuw + (size_t)(ch + 1) * 16384 + g * 16, Mn + g * 16);
      }
    } else {
      #pragma unroll
      for (int i = 0; i < 3; i++) {
        int g = i * 256 + t;
        if (g < 768) gl16((const char*)IDFTm + g * 16, Mn + g * 16);
      }
    }
    int NT = wn2 ? 1 : 2;
    f32x4 acc[2];
    acc[0] = (f32x4){0,0,0,0}; acc[1] = (f32x4){0,0,0,0};
    int lm = wm2 * 16 + lr;
    for (int kk = 0; kk < 256; kk += 32) {
      int kb = kk * 2 + lg * 16;
      short8 af = *(const short8*)(Mc + lm * 512 + (kb ^ SW7b(lm)));
      #pragma unroll
      for (int j = 0; j < 2; j++) {
        if (j < NT) {
          int wf = wn2 * 32 + 16 * j + lr;
          short8 bf = *(const short8*)(FFl + wf * 512 + (kb ^ SW7b(wf)));
          acc[j] = __builtin_amdgcn_mfma_f32_16x16x32_bf16(af, bf, acc[j], 0, 0, 0);
        }
      }
    }
    int co = ch * 32 + wm2 * 16 + lg * 4;
    float4 s4 = *(const float4*)&scp[co];
    float4 h4 = *(const float4*)&shp[co];
    int cc0 = co >> 1;
    #pragma unroll
    for (int j = 0; j < 2; j++) {
      if (j < NT) {
        int wf = wn2 * 32 + 16 * j + lr;
        f32x4 v = acc[j];
        float v0 = fmaxf(v[0] * s4.x + h4.x, 0.f);
        float v1 = fmaxf(v[1] * s4.y + h4.y, 0.f);
        float v2 = fmaxf(v[2] * s4.z + h4.z, 0.f);
        float v3 = fmaxf(v[3] * s4.w + h4.w, 0.f);
        unsigned p0 = (unsigned)f2b(v0) | ((unsigned)f2b(v1) << 16);
        unsigned p1 = (unsigned)f2b(v2) | ((unsigned)f2b(v3) << 16);
        *(unsigned*)(Yl + (cc0 + 0) * 192 + ((4 * wf) ^ SW3b(cc0 + 0))) = p0;
        *(unsigned*)(Yl + (cc0 + 1) * 192 + ((4 * wf) ^ SW3b(cc0 + 1))) = p1;
      }
    }
    __syncthreads();
  }
  {
    f32x4 acc[8];
    #pragma unroll
    for (int nt = 0; nt < 8; nt++) acc[nt] = (f32x4){0,0,0,0};
    int w = wid * 16 + lr;
    for (int kk = 0; kk < 96; kk += 32) {
      int kb = kk * 2 + lg * 16;
      short8 af = *(const short8*)(S0 + w * 192 + (kb ^ SW3b(w)));
      #pragma unroll
      for (int nt = 0; nt < 8; nt++) {
        int cc = 16 * nt + lr;
        short8 bf = *(const short8*)(Yl + cc * 192 + (kb ^ SW3b(cc)));
        acc[nt] = __builtin_amdgcn_mfma_f32_16x16x32_bf16(af, bf, acc[nt], 0, 0, 0);
      }
    }
    int w0 = wid * 16 + lg * 4;
    #pragma unroll
    for (int nt = 0; nt < 8; nt++) {
      int cc = 16 * nt + lr;
      f32x4 v = acc[nt];
      ushort4 o;
      o.x = f2b(v[0]); o.y = f2b(v[1]); o.z = f2b(v[2]); o.w = f2b(v[3]);
      *(ushort4*)(XSO + (((size_t)n * 128 + cc) * 64 + h2) * 64 + w0) = o;
    }
  }
}

// ------------- fused FU + residual + conv2: 78KB LDS, global-A, 2 blocks/CU -------
__global__ __launch_bounds__(1024, 2) void k_fu(const unsigned short* __restrict__ DFTm,
                                                const unsigned short* __restrict__ fuw,
                                                const unsigned short* __restrict__ IDFTm,
                                                const unsigned short* __restrict__ w2m,
                                                const unsigned short* __restrict__ X1c,
                                                const unsigned short* __restrict__ XSO,
                                                const float* __restrict__ scF,
                                                const float* __restrict__ shF,
                                                float* __restrict__ out) {
  __shared__ __align__(16) char SH[79872];
  char* FF = SH;               // 40KB [80 wf][512B] K15; later ACC[128][256B] K15
  char* Yb = SH + 40960;       // 38912B [128 cc][304B]
  int t = threadIdx.x, wid = t >> 6, l = t & 63;
  int lc = l & 31, hf = l >> 5;
  size_t nh = blockIdx.x;
  int n = (int)(nh >> 7), hh = (int)(nh & 127);
  const char* xb = (const char*)X1c + nh * 32768;

  // ---- P1: FF = DFT . X  (A = global DFT plain; B = global X1c K15) --------------
  {
    int mb = wid & 3, nb = wid >> 2;
    int c = nb * 32 + lc;
    short8 bfp[8];
    #pragma unroll
    for (int ks = 0; ks < 8; ks++)
      bfp[ks] = *(const short8*)(xb + (size_t)c * 256 + ((ks * 32 + hf * 16) ^ K15(c)));
    f32x16 acc0 = {0}, acc1 = {0};
    bool x2 = (wid < 4);
    int c2b = wid * 32 + lc;
    #pragma unroll
    for (int ks = 0; ks < 8; ks++) {
      int koe = ks * 16 + hf * 8;
      int m = mb * 32 + lc;
      short8 af = *(const short8*)(DFTm + (size_t)m * 128 + koe);
      acc0 = __builtin_amdgcn_mfma_f32_32x32x16_bf16(af, bfp[ks], acc0, 0, 0, 0);
      if (x2) {
        int m2 = 128 + lc;
        short8 af2 = *(const short8*)(DFTm + (size_t)m2 * 128 + koe);
        short8 bf2 = *(const short8*)(xb + (size_t)c2b * 256 + ((ks * 32 + hf * 16) ^ K15(c2b)));
        acc1 = __builtin_amdgcn_mfma_f32_32x32x16_bf16(af2, bf2, acc1, 0, 0, 0);
      }
    }
    #pragma unroll
    for (int q = 0; q < 4; q++) {
      int wfe = mb * 16 + 4 * q + 2 * hf;
      unsigned p0 = pk2(acc0[4 * q + 0], acc0[4 * q + 1]);
      unsigned p1 = pk2(acc0[4 * q + 2], acc0[4 * q + 3]);
      *(unsigned*)(FF + (size_t)wfe * 512 + ((4 * c) ^ K15(wfe))) = p0;
      *(unsigned*)(FF + (size_t)(wfe + 1) * 512 + ((4 * c) ^ K15(wfe + 1))) = p1;
    }
    if (x2) {
      #pragma unroll
      for (int q = 0; q < 4; q++) {
        int wfe = 64 + 4 * q + 2 * hf;
        unsigned p0 = pk2(acc1[4 * q + 0], acc1[4 * q + 1]);
        unsigned p1 = pk2(acc1[4 * q + 2], acc1[4 * q + 3]);
        *(unsigned*)(FF + (size_t)wfe * 512 + ((4 * c2b) ^ K15(wfe))) = p0;
        *(unsigned*)(FF + (size_t)(wfe + 1) * 512 + ((4 * c2b) ^ K15(wfe + 1))) = p1;
      }
    }
  }
  __syncthreads();
  // ---- P2: Yb = ReLU(BN(fuw . FF))  (A = global fuw plain [256][256]) ------------
  {
    int mb = wid >> 1, odd = wid & 1;
    int co = mb * 32 + lc;
    f32x16 pa = {0}, pb = {0};
    int wfA = (odd ? 32 : 0) + lc;
    int wfB = 64 + lc;          // rows >=80 read Yb garbage; those columns discarded
    #pragma unroll
    for (int ks = 0; ks < 16; ks++) {
      int koe = ks * 16 + hf * 8;
      short8 af = *(const short8*)(fuw + (size_t)co * 256 + koe);
      int kg = ks * 32 + hf * 16;
      short8 bfA = *(const short8*)(FF + (size_t)wfA * 512 + (kg ^ K15(wfA)));
      pa = __builtin_amdgcn_mfma_f32_32x32x16_bf16(af, bfA, pa, 0, 0, 0);
      if (!odd) {
        short8 bfB = *(const short8*)(FF + (size_t)wfB * 512 + (kg ^ K15(wfB)));
        pb = __builtin_amdgcn_mfma_f32_32x32x16_bf16(af, bfB, pb, 0, 0, 0);
      }
    }
    #pragma unroll
    for (int q = 0; q < 4; q++) {
      int co0 = mb * 32 + 8 * q + 4 * hf;
      float4 s4 = *(const float4*)&scF[co0];
      float4 h4 = *(const float4*)&shF[co0];
      int cc0 = co0 >> 1;
      {
        float v0 = fmaxf(pa[4 * q + 0] * s4.x + h4.x, 0.f);
        float v1 = fmaxf(pa[4 * q + 1] * s4.y + h4.y, 0.f);
        float v2 = fmaxf(pa[4 * q + 2] * s4.z + h4.z, 0.f);
        float v3 = fmaxf(pa[4 * q + 3] * s4.w + h4.w, 0.f);
        *(unsigned*)(Yb + (size_t)(cc0 + 0) * 304 + 4 * wfA) = pk2(v0, v1);
        *(unsigned*)(Yb + (size_t)(cc0 + 1) * 304 + 4 * wfA) = pk2(v2, v3);
      }
      if (!odd && lc < 12) {
        float v0 = fmaxf(pb[4 * q + 0] * s4.x + h4.x, 0.f);
        float v1 = fmaxf(pb[4 * q + 1] * s4.y + h4.y, 0.f);
        float v2 = fmaxf(pb[4 * q + 2] * s4.z + h4.z, 0.f);
        float v3 = fmaxf(pb[4 * q + 3] * s4.w + h4.w, 0.f);
        *(unsigned*)(Yb + (size_t)(cc0 + 0) * 304 + 4 * wfB) = pk2(v0, v1);
        *(unsigned*)(Yb + (size_t)(cc0 + 1) * 304 + 4 * wfB) = pk2(v2, v3);
      }
    }
  }
  __syncthreads();
  // ---- P3: ACC = IDFT . Yb + x1 + xs  (A = global IDFT plain; ACC -> FF region) --
  {
    int mb = wid & 3, nb = wid >> 2;
    int mw = mb * 32 + lc;
    int cc = nb * 32 + lc;
    ushort4 rx[4], rs[4];
    #pragma unroll
    for (int q = 0; q < 4; q++) {
      int w0 = mb * 32 + 8 * q + 4 * hf;
      rx[q] = *(const ushort4*)(xb + (size_t)cc * 256 + ((2 * w0) ^ K15(cc)));
      rs[q] = *(const ushort4*)(XSO + (((size_t)n * 128 + cc) * 64 + (hh & 63)) * 64 + (w0 & 63));
    }
    f32x16 p3 = {0};
    #pragma unroll
    for (int ks = 0; ks < 9; ks++) {
      int koe = ks * 16 + hf * 8;
      short8 af = *(const short8*)(IDFTm + (size_t)mw * 192 + koe);
      short8 bf = *(const short8*)(Yb + (size_t)cc * 304 + ks * 32 + hf * 16);
      p3 = __builtin_amdgcn_mfma_f32_32x32x16_bf16(af, bf, p3, 0, 0, 0);
    }
    #pragma unroll
    for (int q = 0; q < 4; q++) {
      int w0 = mb * 32 + 8 * q + 4 * hf;
      float f0 = p3[4 * q + 0] + b2f(rx[q].x) + b2f(rs[q].x);
      float f1 = p3[4 * q + 1] + b2f(rx[q].y) + b2f(rs[q].y);
      float f2_ = p3[4 * q + 2] + b2f(rx[q].z) + b2f(rs[q].z);
      float f3 = p3[4 * q + 3] + b2f(rx[q].w) + b2f(rs[q].w);
      *(unsigned short*)(FF + (size_t)(w0 + 0) * 256 + ((2 * cc) ^ K15(w0 + 0))) = f2b(f0);
      *(unsigned short*)(FF + (size_t)(w0 + 1) * 256 + ((2 * cc) ^ K15(w0 + 1))) = f2b(f1);
      *(unsigned short*)(FF + (size_t)(w0 + 2) * 256 + ((2 * cc) ^ K15(w0 + 2))) = f2b(f2_);
      *(unsigned short*)(FF + (size_t)(w0 + 3) * 256 + ((2 * cc) ^ K15(w0 + 3))) = f2b(f3);
    }
  }
  __syncthreads();
  // ---- P4: out = (ACC . w2^T)  (B = global w2 plain; coalesced stores) -----------
  {
    int mb = wid & 3, nb = wid >> 2;
    int mw = mb * 32 + lc;
    int rco = nb * 32 + lc;
    #pragma unroll
    for (int ck = 0; ck < 2; ck++) {
      f32x16 p4 = {0};
      #pragma unroll
      for (int ks = 0; ks < 8; ks++) {
        int koe = ks * 16 + hf * 8;
        short8 af = *(const short8*)(FF + (size_t)mw * 256 + ((ks * 32 + hf * 16) ^ K15(mw)));
        short8 bf = *(const short8*)(w2m + (size_t)(ck * 128 + rco) * 128 + koe);
        p4 = __builtin_amdgcn_mfma_f32_32x32x16_bf16(af, bf, p4, 0, 0, 0);
      }
      float* obase = out + (nh * 128 + mb * 32) * 256 + ck * 128 + nb * 32 + lc;
      #pragma unroll
      for (int q = 0; q < 4; q++) {
        #pragma unroll
        for (int i = 0; i < 4; i++) {
          int wrow = 8 * q + 4 * hf + i;
          obase[(size_t)wrow * 256] = p4[4 * q + i];
        }
      }
    }
  }
}

extern "C" void kernel_launch(void* const* d_in, const int* in_sizes, int n_in,
                              void* d_out, int out_size, void* d_ws, size_t ws_size,
                              hipStream_t stream) {
  const float* x     = (const float*)d_in[0];
  const float* w1    = (const float*)d_in[1];
  const float* g1    = (const float*)d_in[2];
  const float* b1    = (const float*)d_in[3];
  const float* m1    = (const float*)d_in[4];
  const float* v1    = (const float*)d_in[5];
  const float* fu_w  = (const float*)d_in[6];
  const float* fu_g  = (const float*)d_in[7];
  const float* fu_b  = (const float*)d_in[8];
  const float* fu_m  = (const float*)d_in[9];
  const float* fu_v  = (const float*)d_in[10];
  const float* lfu_w = (const float*)d_in[11];
  const float* lfu_g = (const float*)d_in[12];
  const float* lfu_b = (const float*)d_in[13];
  const float* lfu_m = (const float*)d_in[14];
  const float* lfu_v = (const float*)d_in[15];
  const float* w2    = (const float*)d_in[16];
  float* out = (float*)d_out;

  char* p = (char*)d_ws;
  unsigned short* X1c = (unsigned short*)p; p += 33554432;   // [nh][c][w] bf16, K15 rows
  unsigned short* XSO = (unsigned short*)p; p += 8388608;    // [n][cc][h2][w2] bf16
  unsigned short* w1b   = (unsigned short*)p; p += 65536;
  unsigned short* fuwb  = (unsigned short*)p; p += 131072;   // plain [256][256]
  unsigned short* lfuwb = (unsigned short*)p; p += 131072;
  unsigned short* w2b   = (unsigned short*)p; p += 65536;    // plain [256][128]
  unsigned short* DFTf  = (unsigned short*)p; p += 40960;    // plain [160][128]
  unsigned short* IDFTf = (unsigned short*)p; p += 49152;    // plain [128][192]
  unsigned short* DFTl  = (unsigned short*)p; p += 10240;
  unsigned short* IDFTl = (unsigned short*)p; p += 12288;
  float* sc1 = (float*)p; p += 512;
  float* sh1 = (float*)p; p += 512;
  float* scF = (float*)p; p += 1024;
  float* shF = (float*)p; p += 1024;
  float* scL = (float*)p; p += 1024;
  float* shL = (float*)p; p += 1024;

  k_wt<<<dim3(256), dim3(256), 0, stream>>>(w1, fu_w, lfu_w, w2, g1, b1, m1, v1,
                                            fu_g, fu_b, fu_m, fu_v, lfu_g, lfu_b, lfu_m, lfu_v,
                                            w1b, fuwb, lfuwb, w2b, DFTf, IDFTf, DFTl, IDFTl,
                                            sc1, sh1, scF, shF, scL, shL);
  k_conv1<<<dim3(512), dim3(512), 0, stream>>>(w1b, x, X1c, sc1, sh1);
  k_lfu<<<dim3(512), dim3(256), 0, stream>>>(DFTl, lfuwb, IDFTl, X1c, scL, shL, XSO);
  k_fu<<<dim3(1024), dim3(1024), 0, stream>>>(DFTf, fuwb, IDFTf, w2b, X1c, XSO, scF, shF, out);
}

// Round 18
// 137.676 us; speedup vs baseline: 1.4264x; 1.4264x over previous
//
#include <hip/hip_runtime.h>
#include <math.h>

typedef __attribute__((ext_vector_type(8))) short short8;
typedef __attribute__((ext_vector_type(4))) float f32x4;
typedef __attribute__((ext_vector_type(16))) float f32x16;

#define SW7b(r) (((r) & 7) << 4)
#define SW3b(r) (((r) & 3) << 4)
#define K15(r) (((r) & 15) << 4)
#define K7(r)  (((r) & 7) << 4)

static __device__ __forceinline__ unsigned short f2b(float f){
  unsigned u = __float_as_uint(f);
  u = (u + 0x7FFFu + ((u >> 16) & 1u)) >> 16;
  return (unsigned short)u;
}
static __device__ __forceinline__ float b2f(unsigned short u){
  return __uint_as_float(((unsigned)u) << 16);
}
// packed RNE f32x2 -> bf16x2 (same rounding as f2b, 1 instruction)
static __device__ __forceinline__ unsigned pk2(float a, float b){
  unsigned r;
  asm("v_cvt_pk_bf16_f32 %0, %1, %2" : "=v"(r) : "v"(a), "v"(b));
  return r;
}
static __device__ __forceinline__ void gl16(const void* g, void* l) {
  __builtin_amdgcn_global_load_lds(
      (const __attribute__((address_space(1))) void*)g,
      (__attribute__((address_space(3))) void*)l, 16, 0, 0);
}

// ---------------- weight/matrix prep ----------------------------------------------
__global__ void k_wt(const float* __restrict__ w1, const float* __restrict__ fu_w,
                     const float* __restrict__ lfu_w, const float* __restrict__ w2,
                     const float* __restrict__ g1, const float* __restrict__ b1,
                     const float* __restrict__ m1, const float* __restrict__ v1,
                     const float* __restrict__ fg, const float* __restrict__ fb,
                     const float* __restrict__ fm, const float* __restrict__ fv,
                     const float* __restrict__ lg_, const float* __restrict__ lb_,
                     const float* __restrict__ lm_, const float* __restrict__ lv_,
                     unsigned short* __restrict__ w1b, unsigned short* __restrict__ fuwb,
                     unsigned short* __restrict__ lfuwb, unsigned short* __restrict__ w2b,
                     unsigned short* __restrict__ DFTf, unsigned short* __restrict__ IDFTf,
                     unsigned short* __restrict__ DFTl, unsigned short* __restrict__ IDFTl,
                     float* __restrict__ sc1, float* __restrict__ sh1,
                     float* __restrict__ scF, float* __restrict__ shF,
                     float* __restrict__ scL, float* __restrict__ shL) {
  int t = blockIdx.x * 256 + threadIdx.x;
  const float TPI = 6.283185307179586f;
  if (t < 32768) {
    { int co = t >> 8, k = t & 255; w1b[co * 256 + (k ^ ((co & 7) << 3))] = f2b(w1[t]); }
    { int co = t >> 7, k = t & 127; w2b[co * 128 + (k ^ ((co & 15) << 3))] = f2b(w2[t]); }
  }
  if (t < 65536) {
    int co = t >> 8, k = t & 255;
    fuwb[(size_t)(k >> 6) * 16384 + co * 64 + ((k & 63) ^ ((co & 7) << 3))] = f2b(fu_w[t]);
    lfuwb[co * 256 + (k ^ ((co & 7) << 3))] = f2b(lfu_w[t]);
  }
  if (t < 20480) {                      // DFTf[160][128], element key (m&15)<<3
    int m = t >> 7, w = t & 127; float v = 0.f;
    if (m < 130) {
      int wf = m >> 1; int ph = (wf * w) & 127;
      float ang = TPI * (float)ph / 128.f;
      v = ((m & 1) ? -sinf(ang) : cosf(ang)) * 0.08838834764831845f;
    }
    DFTf[m * 128 + (w ^ ((m & 15) << 3))] = f2b(v);
  }
  if (t < 24576) {                      // IDFTf[128][192] (384B rows), element key (m&7)<<3
    int m = t / 192, k2 = t % 192; float v = 0.f;
    if (k2 < 130) {
      int wf = k2 >> 1; float a = (wf == 0 || wf == 64) ? 1.f : 2.f;
      int ph = (wf * m) & 127;
      float ang = TPI * (float)ph / 128.f;
      v = ((k2 & 1) ? -a * sinf(ang) : a * cosf(ang)) * 0.08838834764831845f;
    }
    IDFTf[m * 192 + (k2 ^ ((m & 7) << 3))] = f2b(v);
  }
  if (t < 5120) {                       // DFTl[80][64], key m&7
    int m = t >> 6, w = t & 63; float v = 0.f;
    if (m < 66) {
      int wf = m >> 1; int ph = (wf * w) & 63;
      float ang = TPI * (float)ph / 64.f;
      v = ((m & 1) ? -sinf(ang) : cosf(ang)) * 0.125f;
    }
    DFTl[m * 64 + (w ^ ((m & 7) << 3))] = f2b(v);
  }
  if (t < 6144) {                       // IDFTl[64][96], key m&3
    int m = t / 96, k2 = t % 96; float v = 0.f;
    if (k2 < 66) {
      int wf = k2 >> 1; float a = (wf == 0 || wf == 32) ? 1.f : 2.f;
      int ph = (wf * m) & 63;
      float ang = TPI * (float)ph / 64.f;
      v = ((k2 & 1) ? -a * sinf(ang) : a * cosf(ang)) * 0.125f;
    }
    IDFTl[m * 96 + (k2 ^ ((m & 3) << 3))] = f2b(v);
  }
  if (t < 128) { float s = g1[t] * rsqrtf(v1[t] + 1e-3f); sc1[t] = s; sh1[t] = b1[t] - m1[t] * s; }
  if (t < 256) { float s = fg[t] * rsqrtf(fv[t] + 1e-3f); scF[t] = s; shF[t] = fb[t] - fm[t] * s; }
  if (t < 256) { float s = lg_[t] * rsqrtf(lv_[t] + 1e-3f); scL[t] = s; shL[t] = lb_[t] - lm_[t] * s; }
}

// ------------- conv1: 512 thr, 2 nh rows/block; epilogue writes K15 layout --------
__global__ __launch_bounds__(512) void k_conv1(const unsigned short* __restrict__ A,
                                               const float* __restrict__ x,
                                               unsigned short* __restrict__ X1c,
                                               const float* __restrict__ scp,
                                               const float* __restrict__ shp) {
  __shared__ __align__(16) char A_s[128 * 512];
  __shared__ __align__(16) char B_s[2][32768];
  int t = threadIdx.x; int wid = t >> 6, l = t & 63;
  int wm = wid >> 2, wn = wid & 3;
  int m0 = wm * 64, n0 = wn * 64;
  int lr = l & 15, lg = l >> 4;
  size_t nh0 = (size_t)blockIdx.x * 2;
  const char* Ab = (const char*)A;
  const char* xrow = (const char*)(x + nh0 * 32768);
  #pragma unroll
  for (int i = 0; i < 8; i++) { int g = i * 512 + t; gl16(Ab + g * 16, A_s + g * 16); }
  #pragma unroll
  for (int i = 0; i < 4; i++) {
    int g = i * 512 + t; int w = g >> 3, o = g & 7;
    gl16(xrow + (size_t)w * 1024 + ((o * 16) ^ SW7b(w)), B_s[0] + g * 16);
  }
  f32x4 acc[4][4];
  #pragma unroll
  for (int mt = 0; mt < 4; mt++)
    #pragma unroll
    for (int nt = 0; nt < 4; nt++) acc[mt][nt] = (f32x4){0.f, 0.f, 0.f, 0.f};
  __syncthreads();
  for (int it = 0; it < 8; it++) {
    int kk = it * 32;
    if (it < 7) {
      #pragma unroll
      for (int i = 0; i < 4; i++) {
        int g = i * 512 + t; int w = g >> 3, o = g & 7;
        gl16(xrow + (size_t)w * 1024 + (kk + 32) * 4 + ((o * 16) ^ SW7b(w)),
             B_s[(it + 1) & 1] + g * 16);
      }
    }
    const char* Bc = B_s[it & 1];
    short8 af[4], bf[4];
    #pragma unroll
    for (int mt = 0; mt < 4; mt++) {
      int m = m0 + 16 * mt + lr;
      af[mt] = *(const short8*)(A_s + m * 512 + ((kk * 2 + lg * 16) ^ SW7b(m)));
    }
    #pragma unroll
    for (int nt = 0; nt < 4; nt++) {
      int w = n0 + 16 * nt + lr;
      float4 f0 = *(const float4*)(Bc + w * 128 + ((lg * 32) ^ SW7b(w)));
      float4 f1 = *(const float4*)(Bc + w * 128 + ((lg * 32 + 16) ^ SW7b(w)));
      short8 bb;
      bb[0] = (short)f2b(f0.x); bb[1] = (short)f2b(f0.y);
      bb[2] = (short)f2b(f0.z); bb[3] = (short)f2b(f0.w);
      bb[4] = (short)f2b(f1.x); bb[5] = (short)f2b(f1.y);
      bb[6] = (short)f2b(f1.z); bb[7] = (short)f2b(f1.w);
      bf[nt] = bb;
    }
    #pragma unroll
    for (int mt = 0; mt < 4; mt++)
      #pragma unroll
      for (int nt = 0; nt < 4; nt++)
        acc[mt][nt] = __builtin_amdgcn_mfma_f32_16x16x32_bf16(af[mt], bf[nt], acc[mt][nt], 0, 0, 0);
    __syncthreads();
  }
  #pragma unroll
  for (int nt = 0; nt < 4; nt++) {
    int wcol = n0 + 16 * nt + lr;
    char* xout = (char*)X1c + (nh0 + (wcol >> 7)) * 32768;
    int w = wcol & 127;
    #pragma unroll
    for (int mt = 0; mt < 4; mt++) {
      int rb = m0 + 16 * mt + lg * 4;
      float4 s4 = *(const float4*)&scp[rb];
      float4 h4 = *(const float4*)&shp[rb];
      f32x4 v = acc[mt][nt];
      *(unsigned short*)(xout + (rb + 0) * 256 + ((w * 2) ^ K15(rb + 0))) = f2b(fmaxf(v[0] * s4.x + h4.x, 0.f));
      *(unsigned short*)(xout + (rb + 1) * 256 + ((w * 2) ^ K15(rb + 1))) = f2b(fmaxf(v[1] * s4.y + h4.y, 0.f));
      *(unsigned short*)(xout + (rb + 2) * 256 + ((w * 2) ^ K15(rb + 2))) = f2b(fmaxf(v[2] * s4.z + h4.z, 0.f));
      *(unsigned short*)(xout + (rb + 3) * 256 + ((w * 2) ^ K15(rb + 3))) = f2b(fmaxf(v[3] * s4.w + h4.w, 0.f));
    }
  }
}

// ------------- fused local FU: ping-pong chunk staging, P1-B from global ----------
__global__ __launch_bounds__(256) void k_lfu(const unsigned short* __restrict__ DFTm,
                                             const unsigned short* __restrict__ lfuw,
                                             const unsigned short* __restrict__ IDFTm,
                                             const unsigned short* __restrict__ X1c,
                                             const float* __restrict__ scp,
                                             const float* __restrict__ shp,
                                             unsigned short* __restrict__ XSO) {
  __shared__ __align__(16) char SH[81920];
  char* M   = SH;
  char* S0  = SH + 16384;
  char* FFl = SH + 32768;
  char* Yl  = SH + 57344;
  int t = threadIdx.x, wid = t >> 6, l = t & 63, lr = l & 15, lg = l >> 4;
  int b = blockIdx.x; int n = b >> 6, h2 = b & 63;
  {
    #pragma unroll
    for (int i = 0; i < 3; i++) { int g = i * 256 + t; if (g < 640) gl16((const char*)DFTm + g * 16, M + g * 16); }
    #pragma unroll
    for (int i = 0; i < 4; i++) { int g = i * 256 + t; gl16((const char*)lfuw + g * 16, S0 + g * 16); }
    #pragma unroll
    for (int i = 0; i < 8; i++) {
      int u = i * 256 + t;
      if (u < 1920) *(unsigned*)(FFl + 33 * 512 + u * 4) = 0u;
    }
  }
  __syncthreads();
  {
    short8 bfp[2][2];
    #pragma unroll
    for (int nt = 0; nt < 2; nt++) {
      int c2 = wid * 32 + 16 * nt + lr;
      int c0 = c2 & 31, hb = (c2 >> 5) & 1, wbq = (c2 >> 6) & 1;
      int half = wbq ^ ((c0 >> 3) & 1);
      const char* base = (const char*)X1c +
          ((size_t)(n * 128 + hb * 64 + h2) * 128 + c0) * 256 + half * 128;
      #pragma unroll
      for (int ki = 0; ki < 2; ki++) {
        int kb = ki * 64 + lg * 16;
        bfp[nt][ki] = *(const short8*)(base + (kb ^ SW7b(c2)));
      }
    }
    f32x4 acc[5][2];
    #pragma unroll
    for (int mt = 0; mt < 5; mt++) { acc[mt][0] = (f32x4){0,0,0,0}; acc[mt][1] = (f32x4){0,0,0,0}; }
    #pragma unroll
    for (int ki = 0; ki < 2; ki++) {
      int kb = ki * 64 + lg * 16;
      #pragma unroll
      for (int mt = 0; mt < 5; mt++) {
        int m = 16 * mt + lr;
        short8 af = *(const short8*)(M + m * 128 + (kb ^ SW7b(m)));
        #pragma unroll
        for (int nt = 0; nt < 2; nt++)
          acc[mt][nt] = __builtin_amdgcn_mfma_f32_16x16x32_bf16(af, bfp[nt][ki], acc[mt][nt], 0, 0, 0);
      }
    }
    #pragma unroll
    for (int nt = 0; nt < 2; nt++) {
      int c2 = wid * 32 + 16 * nt + lr;
      #pragma unroll
      for (int mt = 0; mt < 5; mt++) {
        int rb = 16 * mt + lg * 4;
        int wf0 = rb >> 1;
        f32x4 v = acc[mt][nt];
        if (wf0 < 33) {
          unsigned pk = (unsigned)f2b(v[0]) | ((unsigned)f2b(v[1]) << 16);
          *(unsigned*)(FFl + wf0 * 512 + ((4 * c2) ^ SW7b(wf0))) = pk;
        }
        if (wf0 + 1 < 33) {
          unsigned pk = (unsigned)f2b(v[2]) | ((unsigned)f2b(v[3]) << 16);
          *(unsigned*)(FFl + (wf0 + 1) * 512 + ((4 * c2) ^ SW7b(wf0 + 1))) = pk;
        }
      }
    }
  }
  __syncthreads();
  int wm2 = wid >> 1, wn2 = wid & 1;
  for (int ch = 0; ch < 8; ch++) {
    char* Mc = (ch & 1) ? M : S0;
    char* Mn = (ch & 1) ? S0 : M;
    if (ch < 7) {
      #pragma unroll
      for (int i = 0; i < 4; i++) {
        int g = i * 256 + t;
        gl16((const char*)lfuw + (size_t)(ch + 1) * 16384 + g * 16, Mn + g * 16);
      }
    } else {
      #pragma unroll
      for (int i = 0; i < 3; i++) {
        int g = i * 256 + t;
        if (g < 768) gl16((const char*)IDFTm + g * 16, Mn + g * 16);
      }
    }
    int NT = wn2 ? 1 : 2;
    f32x4 acc[2];
    acc[0] = (f32x4){0,0,0,0}; acc[1] = (f32x4){0,0,0,0};
    int lm = wm2 * 16 + lr;
    for (int kk = 0; kk < 256; kk += 32) {
      int kb = kk * 2 + lg * 16;
      short8 af = *(const short8*)(Mc + lm * 512 + (kb ^ SW7b(lm)));
      #pragma unroll
      for (int j = 0; j < 2; j++) {
        if (j < NT) {
          int wf = wn2 * 32 + 16 * j + lr;
          short8 bf = *(const short8*)(FFl + wf * 512 + (kb ^ SW7b(wf)));
          acc[j] = __builtin_amdgcn_mfma_f32_16x16x32_bf16(af, bf, acc[j], 0, 0, 0);
        }
      }
    }
    int co = ch * 32 + wm2 * 16 + lg * 4;
    float4 s4 = *(const float4*)&scp[co];
    float4 h4 = *(const float4*)&shp[co];
    int cc0 = co >> 1;
    #pragma unroll
    for (int j = 0; j < 2; j++) {
      if (j < NT) {
        int wf = wn2 * 32 + 16 * j + lr;
        f32x4 v = acc[j];
        float v0 = fmaxf(v[0] * s4.x + h4.x, 0.f);
        float v1 = fmaxf(v[1] * s4.y + h4.y, 0.f);
        float v2 = fmaxf(v[2] * s4.z + h4.z, 0.f);
        float v3 = fmaxf(v[3] * s4.w + h4.w, 0.f);
        unsigned p0 = (unsigned)f2b(v0) | ((unsigned)f2b(v1) << 16);
        unsigned p1 = (unsigned)f2b(v2) | ((unsigned)f2b(v3) << 16);
        *(unsigned*)(Yl + (cc0 + 0) * 192 + ((4 * wf) ^ SW3b(cc0 + 0))) = p0;
        *(unsigned*)(Yl + (cc0 + 1) * 192 + ((4 * wf) ^ SW3b(cc0 + 1))) = p1;
      }
    }
    __syncthreads();
  }
  {
    f32x4 acc[8];
    #pragma unroll
    for (int nt = 0; nt < 8; nt++) acc[nt] = (f32x4){0,0,0,0};
    int w = wid * 16 + lr;
    for (int kk = 0; kk < 96; kk += 32) {
      int kb = kk * 2 + lg * 16;
      short8 af = *(const short8*)(S0 + w * 192 + (kb ^ SW3b(w)));
      #pragma unroll
      for (int nt = 0; nt < 8; nt++) {
        int cc = 16 * nt + lr;
        short8 bf = *(const short8*)(Yl + cc * 192 + (kb ^ SW3b(cc)));
        acc[nt] = __builtin_amdgcn_mfma_f32_16x16x32_bf16(af, bf, acc[nt], 0, 0, 0);
      }
    }
    int w0 = wid * 16 + lg * 4;
    #pragma unroll
    for (int nt = 0; nt < 8; nt++) {
      int cc = 16 * nt + lr;
      f32x4 v = acc[nt];
      ushort4 o;
      o.x = f2b(v[0]); o.y = f2b(v[1]); o.z = f2b(v[2]); o.w = f2b(v[3]);
      *(ushort4*)(XSO + (((size_t)n * 128 + cc) * 64 + h2) * 64 + w0) = o;
    }
  }
}

// ------------- fused FU + residual + conv2: 32x32x16; cvt_pk epilogues ------------
__global__ __launch_bounds__(1024, 4) void k_fu(const unsigned short* __restrict__ DFTm,
                                                const unsigned short* __restrict__ fuw,
                                                const unsigned short* __restrict__ IDFTm,
                                                const unsigned short* __restrict__ w2m,
                                                const unsigned short* __restrict__ X1c,
                                                const unsigned short* __restrict__ XSO,
                                                const float* __restrict__ scF,
                                                const float* __restrict__ shF,
                                                float* __restrict__ out) {
  __shared__ __align__(16) char SH[161792];
  char* R0 = SH;               // 40KB: DFT -> fuw kc1 -> fuw kc3 -> w2 c1
  char* R1 = SH + 40960;       // 32KB: fuw kc0 -> fuw kc2 -> w2 c0
  char* R2 = SH + 73728;       // 48KB: FF[96][512B] (K15) -> IDFT[128][384B] (K7)
  char* R3 = SH + 122880;      // 38912B: Yb[128][304B] -> ACC[128][256B] (K15)
  int t = threadIdx.x, wid = t >> 6, l = t & 63;
  int lc = l & 31, hf = l >> 5;
  size_t nh = blockIdx.x;
  int n = (int)(nh >> 7), hh = (int)(nh & 127);
  const char* xb = (const char*)X1c + nh * 32768;

  #pragma unroll
  for (int i = 0; i < 3; i++) {
    int g = i * 1024 + t;
    if (g < 2560) gl16((const char*)DFTm + (size_t)g * 16, R0 + g * 16);
  }
  *(unsigned*)(R2 + 80 * 512 + t * 8) = 0u;
  *(unsigned*)(R2 + 80 * 512 + t * 8 + 4) = 0u;
  __syncthreads();
  // ---- P1: FF = DFT . X  (A=R0, B=global X1c). stage fuw kc0 -> R1 ---------------
  {
    #pragma unroll
    for (int i = 0; i < 2; i++) {
      int g = i * 1024 + t;
      gl16((const char*)fuw + (size_t)g * 16, R1 + g * 16);
    }
    int mb = wid & 3, nb = wid >> 2;
    int c = nb * 32 + lc;
    short8 bfp[8];
    #pragma unroll
    for (int ks = 0; ks < 8; ks++)
      bfp[ks] = *(const short8*)(xb + (size_t)c * 256 + ((ks * 32 + hf * 16) ^ K15(c)));
    f32x16 acc0 = {0}, acc1 = {0};
    bool x2 = (wid < 4);
    int c2b = wid * 32 + lc;
    #pragma unroll
    for (int ks = 0; ks < 8; ks++) {
      int ko = ks * 32 + hf * 16;
      int m = mb * 32 + lc;
      short8 af = *(const short8*)(R0 + (size_t)m * 256 + (ko ^ K15(m)));
      acc0 = __builtin_amdgcn_mfma_f32_32x32x16_bf16(af, bfp[ks], acc0, 0, 0, 0);
      if (x2) {
        int m2 = 128 + lc;
        short8 af2 = *(const short8*)(R0 + (size_t)m2 * 256 + (ko ^ K15(m2)));
        short8 bf2 = *(const short8*)(xb + (size_t)c2b * 256 + (ko ^ K15(c2b)));
        acc1 = __builtin_amdgcn_mfma_f32_32x32x16_bf16(af2, bf2, acc1, 0, 0, 0);
      }
    }
    #pragma unroll
    for (int q = 0; q < 4; q++) {
      int wfe = mb * 16 + 4 * q + 2 * hf;
      unsigned p0 = pk2(acc0[4 * q + 0], acc0[4 * q + 1]);
      unsigned p1 = pk2(acc0[4 * q + 2], acc0[4 * q + 3]);
      *(unsigned*)(R2 + (size_t)wfe * 512 + ((4 * c) ^ K15(wfe))) = p0;
      *(unsigned*)(R2 + (size_t)(wfe + 1) * 512 + ((4 * c) ^ K15(wfe + 1))) = p1;
    }
    if (x2) {
      #pragma unroll
      for (int q = 0; q < 4; q++) {
        int wfe = 64 + 4 * q + 2 * hf;
        unsigned p0 = pk2(acc1[4 * q + 0], acc1[4 * q + 1]);
        unsigned p1 = pk2(acc1[4 * q + 2], acc1[4 * q + 3]);
        *(unsigned*)(R2 + (size_t)wfe * 512 + ((4 * c2b) ^ K15(wfe))) = p0;
        *(unsigned*)(R2 + (size_t)(wfe + 1) * 512 + ((4 * c2b) ^ K15(wfe + 1))) = p1;
      }
    }
  }
  // ---- P2: Y = ReLU(BN(fuw . FF)), K-sliced chunks, acc persists -----------------
  {
    int mb = wid >> 1, odd = wid & 1;
    int co = mb * 32 + lc;
    f32x16 pa = {0}, pb = {0};
    int wfA = (odd ? 32 : 0) + lc;
    int wfB = 64 + lc;
    #pragma unroll
    for (int ch = 0; ch < 4; ch++) {
      char* Mc = (ch & 1) ? R0 : R1;
      char* Mn = (ch & 1) ? R1 : R0;
      __syncthreads();
      if (ch < 3) {
        #pragma unroll
        for (int i = 0; i < 2; i++) {
          int g = i * 1024 + t;
          gl16((const char*)fuw + (size_t)(ch + 1) * 32768 + (size_t)g * 16, Mn + g * 16);
        }
      } else {
        #pragma unroll
        for (int i = 0; i < 2; i++) {
          int g = i * 1024 + t;
          gl16((const char*)w2m + (size_t)g * 16, Mn + g * 16);
        }
      }
      #pragma unroll
      for (int ks = 0; ks < 4; ks++) {
        int ko = ks * 32 + hf * 16;
        short8 af = *(const short8*)(Mc + (size_t)co * 128 + (ko ^ K7(co)));
        int kg = (ch * 4 + ks) * 32 + hf * 16;
        short8 bfA = *(const short8*)(R2 + (size_t)wfA * 512 + (kg ^ K15(wfA)));
        pa = __builtin_amdgcn_mfma_f32_32x32x16_bf16(af, bfA, pa, 0, 0, 0);
        if (!odd) {
          short8 bfB = *(const short8*)(R2 + (size_t)wfB * 512 + (kg ^ K15(wfB)));
          pb = __builtin_amdgcn_mfma_f32_32x32x16_bf16(af, bfB, pb, 0, 0, 0);
        }
      }
    }
    #pragma unroll
    for (int q = 0; q < 4; q++) {
      int co0 = mb * 32 + 8 * q + 4 * hf;
      float4 s4 = *(const float4*)&scF[co0];
      float4 h4 = *(const float4*)&shF[co0];
      int cc0 = co0 >> 1;
      {
        float v0 = fmaxf(pa[4 * q + 0] * s4.x + h4.x, 0.f);
        float v1 = fmaxf(pa[4 * q + 1] * s4.y + h4.y, 0.f);
        float v2 = fmaxf(pa[4 * q + 2] * s4.z + h4.z, 0.f);
        float v3 = fmaxf(pa[4 * q + 3] * s4.w + h4.w, 0.f);
        *(unsigned*)(R3 + (size_t)(cc0 + 0) * 304 + 4 * wfA) = pk2(v0, v1);
        *(unsigned*)(R3 + (size_t)(cc0 + 1) * 304 + 4 * wfA) = pk2(v2, v3);
      }
      if (!odd && lc < 12) {
        float v0 = fmaxf(pb[4 * q + 0] * s4.x + h4.x, 0.f);
        float v1 = fmaxf(pb[4 * q + 1] * s4.y + h4.y, 0.f);
        float v2 = fmaxf(pb[4 * q + 2] * s4.z + h4.z, 0.f);
        float v3 = fmaxf(pb[4 * q + 3] * s4.w + h4.w, 0.f);
        *(unsigned*)(R3 + (size_t)(cc0 + 0) * 304 + 4 * wfB) = pk2(v0, v1);
        *(unsigned*)(R3 + (size_t)(cc0 + 1) * 304 + 4 * wfB) = pk2(v2, v3);
      }
    }
  }
  __syncthreads();
  #pragma unroll
  for (int i = 0; i < 3; i++) {
    int g = i * 1024 + t;
    gl16((const char*)IDFTm + (size_t)g * 16, R2 + g * 16);
  }
  #pragma unroll
  for (int i = 0; i < 2; i++) {
    int g = i * 1024 + t;
    gl16((const char*)w2m + 32768 + (size_t)g * 16, R0 + g * 16);
  }
  __syncthreads();
  // ---- P3: ACC = IDFT . Y + x1 + xs (A=R2 384B K7, B=R3 304B) --------------------
  {
    int mb = wid & 3, nb = wid >> 2;
    int mw = mb * 32 + lc;
    int cc = nb * 32 + lc;
    ushort4 rx[4], rs[4];
    #pragma unroll
    for (int q = 0; q < 4; q++) {
      int w0 = mb * 32 + 8 * q + 4 * hf;
      rx[q] = *(const ushort4*)(xb + (size_t)cc * 256 + ((2 * w0) ^ K15(cc)));
      rs[q] = *(const ushort4*)(XSO + (((size_t)n * 128 + cc) * 64 + (hh & 63)) * 64 + (w0 & 63));
    }
    f32x16 p3 = {0};
    #pragma unroll
    for (int ks = 0; ks < 9; ks++) {
      int ko = ks * 32 + hf * 16;
      short8 af = *(const short8*)(R2 + (size_t)mw * 384 + (ko ^ K7(mw)));
      short8 bf = *(const short8*)(R3 + (size_t)cc * 304 + ko);
      p3 = __builtin_amdgcn_mfma_f32_32x32x16_bf16(af, bf, p3, 0, 0, 0);
    }
    __syncthreads();
    #pragma unroll
    for (int q = 0; q < 4; q++) {
      int w0 = mb * 32 + 8 * q + 4 * hf;
      float f0 = p3[4 * q + 0] + b2f(rx[q].x) + b2f(rs[q].x);
      float f1 = p3[4 * q + 1] + b2f(rx[q].y) + b2f(rs[q].y);
      float f2_ = p3[4 * q + 2] + b2f(rx[q].z) + b2f(rs[q].z);
      float f3 = p3[4 * q + 3] + b2f(rx[q].w) + b2f(rs[q].w);
      *(unsigned short*)(R3 + (size_t)(w0 + 0) * 256 + ((2 * cc) ^ K15(w0 + 0))) = f2b(f0);
      *(unsigned short*)(R3 + (size_t)(w0 + 1) * 256 + ((2 * cc) ^ K15(w0 + 1))) = f2b(f1);
      *(unsigned short*)(R3 + (size_t)(w0 + 2) * 256 + ((2 * cc) ^ K15(w0 + 2))) = f2b(f2_);
      *(unsigned short*)(R3 + (size_t)(w0 + 3) * 256 + ((2 * cc) ^ K15(w0 + 3))) = f2b(f3);
    }
  }
  __syncthreads();
  // ---- P4: out = (ACC . w2^T), m=w, n=co2 -> coalesced scalar stores -------------
  {
    int mb = wid & 3, nb = wid >> 2;
    int mw = mb * 32 + lc;
    int rco = nb * 32 + lc;
    #pragma unroll
    for (int ck = 0; ck < 2; ck++) {
      const char* Mc = ck ? R0 : R1;
      f32x16 p4 = {0};
      #pragma unroll
      for (int ks = 0; ks < 8; ks++) {
        int ko = ks * 32 + hf * 16;
        short8 af = *(const short8*)(R3 + (size_t)mw * 256 + (ko ^ K15(mw)));
        short8 bf = *(const short8*)(Mc + (size_t)rco * 256 + (ko ^ K15(rco)));
        p4 = __builtin_amdgcn_mfma_f32_32x32x16_bf16(af, bf, p4, 0, 0, 0);
      }
      float* obase = out + (nh * 128 + mb * 32) * 256 + ck * 128 + nb * 32 + lc;
      #pragma unroll
      for (int q = 0; q < 4; q++) {
        #pragma unroll
        for (int i = 0; i < 4; i++) {
          int wrow = 8 * q + 4 * hf + i;
          obase[(size_t)wrow * 256] = p4[4 * q + i];
        }
      }
    }
  }
}

extern "C" void kernel_launch(void* const* d_in, const int* in_sizes, int n_in,
                              void* d_out, int out_size, void* d_ws, size_t ws_size,
                              hipStream_t stream) {
  const float* x     = (const float*)d_in[0];
  const float* w1    = (const float*)d_in[1];
  const float* g1    = (const float*)d_in[2];
  const float* b1    = (const float*)d_in[3];
  const float* m1    = (const float*)d_in[4];
  const float* v1    = (const float*)d_in[5];
  const float* fu_w  = (const float*)d_in[6];
  const float* fu_g  = (const float*)d_in[7];
  const float* fu_b  = (const float*)d_in[8];
  const float* fu_m  = (const float*)d_in[9];
  const float* fu_v  = (const float*)d_in[10];
  const float* lfu_w = (const float*)d_in[11];
  const float* lfu_g = (const float*)d_in[12];
  const float* lfu_b = (const float*)d_in[13];
  const float* lfu_m = (const float*)d_in[14];
  const float* lfu_v = (const float*)d_in[15];
  const float* w2    = (const float*)d_in[16];
  float* out = (float*)d_out;

  char* p = (char*)d_ws;
  unsigned short* X1c = (unsigned short*)p; p += 33554432;   // [nh][c][w] bf16, K15 rows
  unsigned short* XSO = (unsigned short*)p; p += 8388608;    // [n][cc][h2][w2] bf16
  unsigned short* w1b   = (unsigned short*)p; p += 65536;
  unsigned short* fuwb  = (unsigned short*)p; p += 131072;   // k-sliced
  unsigned short* lfuwb = (unsigned short*)p; p += 131072;
  unsigned short* w2b   = (unsigned short*)p; p += 65536;
  unsigned short* DFTf  = (unsigned short*)p; p += 40960;    // [160][128]
  unsigned short* IDFTf = (unsigned short*)p; p += 49152;    // [128][192]
  unsigned short* DFTl  = (unsigned short*)p; p += 10240;
  unsigned short* IDFTl = (unsigned short*)p; p += 12288;
  float* sc1 = (float*)p; p += 512;
  float* sh1 = (float*)p; p += 512;
  float* scF = (float*)p; p += 1024;
  float* shF = (float*)p; p += 1024;
  float* scL = (float*)p; p += 1024;
  float* shL = (float*)p; p += 1024;

  k_wt<<<dim3(256), dim3(256), 0, stream>>>(w1, fu_w, lfu_w, w2, g1, b1, m1, v1,
                                            fu_g, fu_b, fu_m, fu_v, lfu_g, lfu_b, lfu_m, lfu_v,
                                            w1b, fuwb, lfuwb, w2b, DFTf, IDFTf, DFTl, IDFTl,
                                            sc1, sh1, scF, shF, scL, shL);
  k_conv1<<<dim3(512), dim3(512), 0, stream>>>(w1b, x, X1c, sc1, sh1);
  k_lfu<<<dim3(512), dim3(256), 0, stream>>>(DFTl, lfuwb, IDFTl, X1c, scL, shL, XSO);
  k_fu<<<dim3(1024), dim3(1024), 0, stream>>>(DFTf, fuwb, IDFTf, w2b, X1c, XSO, scF, shF, out);
}

// Round 19
// 137.333 us; speedup vs baseline: 1.4300x; 1.0025x over previous
//
#include <hip/hip_runtime.h>
#include <math.h>

typedef __attribute__((ext_vector_type(8))) short short8;
typedef __attribute__((ext_vector_type(4))) float f32x4;
typedef __attribute__((ext_vector_type(16))) float f32x16;

#define SW7b(r) (((r) & 7) << 4)
#define SW3b(r) (((r) & 3) << 4)
#define K15(r) (((r) & 15) << 4)
#define K7(r)  (((r) & 7) << 4)

static __device__ __forceinline__ unsigned short f2b(float f){
  unsigned u = __float_as_uint(f);
  u = (u + 0x7FFFu + ((u >> 16) & 1u)) >> 16;
  return (unsigned short)u;
}
static __device__ __forceinline__ float b2f(unsigned short u){
  return __uint_as_float(((unsigned)u) << 16);
}
// packed RNE f32x2 -> bf16x2 (same rounding as f2b, 1 instruction)
static __device__ __forceinline__ unsigned pk2(float a, float b){
  unsigned r;
  asm("v_cvt_pk_bf16_f32 %0, %1, %2" : "=v"(r) : "v"(a), "v"(b));
  return r;
}
static __device__ __forceinline__ void gl16(const void* g, void* l) {
  __builtin_amdgcn_global_load_lds(
      (const __attribute__((address_space(1))) void*)g,
      (__attribute__((address_space(3))) void*)l, 16, 0, 0);
}

// ---------------- weight/matrix prep ----------------------------------------------
__global__ void k_wt(const float* __restrict__ w1, const float* __restrict__ fu_w,
                     const float* __restrict__ lfu_w, const float* __restrict__ w2,
                     const float* __restrict__ g1, const float* __restrict__ b1,
                     const float* __restrict__ m1, const float* __restrict__ v1,
                     const float* __restrict__ fg, const float* __restrict__ fb,
                     const float* __restrict__ fm, const float* __restrict__ fv,
                     const float* __restrict__ lg_, const float* __restrict__ lb_,
                     const float* __restrict__ lm_, const float* __restrict__ lv_,
                     unsigned short* __restrict__ w1b, unsigned short* __restrict__ fuwb,
                     unsigned short* __restrict__ lfuwb, unsigned short* __restrict__ w2b,
                     unsigned short* __restrict__ DFTf, unsigned short* __restrict__ IDFTf,
                     unsigned short* __restrict__ DFTl, unsigned short* __restrict__ IDFTl,
                     float* __restrict__ sc1, float* __restrict__ sh1,
                     float* __restrict__ scF, float* __restrict__ shF,
                     float* __restrict__ scL, float* __restrict__ shL) {
  int t = blockIdx.x * 256 + threadIdx.x;
  const float TPI = 6.283185307179586f;
  if (t < 32768) {
    { int co = t >> 8, k = t & 255; w1b[co * 256 + (k ^ ((co & 7) << 3))] = f2b(w1[t]); }
    { int co = t >> 7, k = t & 127; w2b[co * 128 + (k ^ ((co & 15) << 3))] = f2b(w2[t]); }
  }
  if (t < 65536) {
    int co = t >> 8, k = t & 255;
    fuwb[(size_t)(k >> 6) * 16384 + co * 64 + ((k & 63) ^ ((co & 7) << 3))] = f2b(fu_w[t]);
    lfuwb[co * 256 + (k ^ ((co & 7) << 3))] = f2b(lfu_w[t]);
  }
  if (t < 20480) {                      // DFTf[160][128], element key (m&15)<<3
    int m = t >> 7, w = t & 127; float v = 0.f;
    if (m < 130) {
      int wf = m >> 1; int ph = (wf * w) & 127;
      float ang = TPI * (float)ph / 128.f;
      v = ((m & 1) ? -sinf(ang) : cosf(ang)) * 0.08838834764831845f;
    }
    DFTf[m * 128 + (w ^ ((m & 15) << 3))] = f2b(v);
  }
  if (t < 24576) {                      // IDFTf[128][192] (384B rows), element key (m&7)<<3
    int m = t / 192, k2 = t % 192; float v = 0.f;
    if (k2 < 130) {
      int wf = k2 >> 1; float a = (wf == 0 || wf == 64) ? 1.f : 2.f;
      int ph = (wf * m) & 127;
      float ang = TPI * (float)ph / 128.f;
      v = ((k2 & 1) ? -a * sinf(ang) : a * cosf(ang)) * 0.08838834764831845f;
    }
    IDFTf[m * 192 + (k2 ^ ((m & 7) << 3))] = f2b(v);
  }
  if (t < 5120) {                       // DFTl[80][64], key m&7
    int m = t >> 6, w = t & 63; float v = 0.f;
    if (m < 66) {
      int wf = m >> 1; int ph = (wf * w) & 63;
      float ang = TPI * (float)ph / 64.f;
      v = ((m & 1) ? -sinf(ang) : cosf(ang)) * 0.125f;
    }
    DFTl[m * 64 + (w ^ ((m & 7) << 3))] = f2b(v);
  }
  if (t < 6144) {                       // IDFTl[64][96], key m&3
    int m = t / 96, k2 = t % 96; float v = 0.f;
    if (k2 < 66) {
      int wf = k2 >> 1; float a = (wf == 0 || wf == 32) ? 1.f : 2.f;
      int ph = (wf * m) & 63;
      float ang = TPI * (float)ph / 64.f;
      v = ((k2 & 1) ? -a * sinf(ang) : a * cosf(ang)) * 0.125f;
    }
    IDFTl[m * 96 + (k2 ^ ((m & 3) << 3))] = f2b(v);
  }
  if (t < 128) { float s = g1[t] * rsqrtf(v1[t] + 1e-3f); sc1[t] = s; sh1[t] = b1[t] - m1[t] * s; }
  if (t < 256) { float s = fg[t] * rsqrtf(fv[t] + 1e-3f); scF[t] = s; shF[t] = fb[t] - fm[t] * s; }
  if (t < 256) { float s = lg_[t] * rsqrtf(lv_[t] + 1e-3f); scL[t] = s; shL[t] = lb_[t] - lm_[t] * s; }
}

// ------------- conv1: 512 thr, 2 nh rows/block; epilogue writes K15 layout --------
__global__ __launch_bounds__(512) void k_conv1(const unsigned short* __restrict__ A,
                                               const float* __restrict__ x,
                                               unsigned short* __restrict__ X1c,
                                               const float* __restrict__ scp,
                                               const float* __restrict__ shp) {
  __shared__ __align__(16) char A_s[128 * 512];
  __shared__ __align__(16) char B_s[2][32768];
  int t = threadIdx.x; int wid = t >> 6, l = t & 63;
  int wm = wid >> 2, wn = wid & 3;
  int m0 = wm * 64, n0 = wn * 64;
  int lr = l & 15, lg = l >> 4;
  size_t nh0 = (size_t)blockIdx.x * 2;
  const char* Ab = (const char*)A;
  const char* xrow = (const char*)(x + nh0 * 32768);
  #pragma unroll
  for (int i = 0; i < 8; i++) { int g = i * 512 + t; gl16(Ab + g * 16, A_s + g * 16); }
  #pragma unroll
  for (int i = 0; i < 4; i++) {
    int g = i * 512 + t; int w = g >> 3, o = g & 7;
    gl16(xrow + (size_t)w * 1024 + ((o * 16) ^ SW7b(w)), B_s[0] + g * 16);
  }
  f32x4 acc[4][4];
  #pragma unroll
  for (int mt = 0; mt < 4; mt++)
    #pragma unroll
    for (int nt = 0; nt < 4; nt++) acc[mt][nt] = (f32x4){0.f, 0.f, 0.f, 0.f};
  __syncthreads();
  for (int it = 0; it < 8; it++) {
    int kk = it * 32;
    if (it < 7) {
      #pragma unroll
      for (int i = 0; i < 4; i++) {
        int g = i * 512 + t; int w = g >> 3, o = g & 7;
        gl16(xrow + (size_t)w * 1024 + (kk + 32) * 4 + ((o * 16) ^ SW7b(w)),
             B_s[(it + 1) & 1] + g * 16);
      }
    }
    const char* Bc = B_s[it & 1];
    short8 af[4], bf[4];
    #pragma unroll
    for (int mt = 0; mt < 4; mt++) {
      int m = m0 + 16 * mt + lr;
      af[mt] = *(const short8*)(A_s + m * 512 + ((kk * 2 + lg * 16) ^ SW7b(m)));
    }
    #pragma unroll
    for (int nt = 0; nt < 4; nt++) {
      int w = n0 + 16 * nt + lr;
      float4 f0 = *(const float4*)(Bc + w * 128 + ((lg * 32) ^ SW7b(w)));
      float4 f1 = *(const float4*)(Bc + w * 128 + ((lg * 32 + 16) ^ SW7b(w)));
      short8 bb;
      bb[0] = (short)f2b(f0.x); bb[1] = (short)f2b(f0.y);
      bb[2] = (short)f2b(f0.z); bb[3] = (short)f2b(f0.w);
      bb[4] = (short)f2b(f1.x); bb[5] = (short)f2b(f1.y);
      bb[6] = (short)f2b(f1.z); bb[7] = (short)f2b(f1.w);
      bf[nt] = bb;
    }
    #pragma unroll
    for (int mt = 0; mt < 4; mt++)
      #pragma unroll
      for (int nt = 0; nt < 4; nt++)
        acc[mt][nt] = __builtin_amdgcn_mfma_f32_16x16x32_bf16(af[mt], bf[nt], acc[mt][nt], 0, 0, 0);
    __syncthreads();
  }
  #pragma unroll
  for (int nt = 0; nt < 4; nt++) {
    int wcol = n0 + 16 * nt + lr;
    char* xout = (char*)X1c + (nh0 + (wcol >> 7)) * 32768;
    int w = wcol & 127;
    #pragma unroll
    for (int mt = 0; mt < 4; mt++) {
      int rb = m0 + 16 * mt + lg * 4;
      float4 s4 = *(const float4*)&scp[rb];
      float4 h4 = *(const float4*)&shp[rb];
      f32x4 v = acc[mt][nt];
      *(unsigned short*)(xout + (rb + 0) * 256 + ((w * 2) ^ K15(rb + 0))) = f2b(fmaxf(v[0] * s4.x + h4.x, 0.f));
      *(unsigned short*)(xout + (rb + 1) * 256 + ((w * 2) ^ K15(rb + 1))) = f2b(fmaxf(v[1] * s4.y + h4.y, 0.f));
      *(unsigned short*)(xout + (rb + 2) * 256 + ((w * 2) ^ K15(rb + 2))) = f2b(fmaxf(v[2] * s4.z + h4.z, 0.f));
      *(unsigned short*)(xout + (rb + 3) * 256 + ((w * 2) ^ K15(rb + 3))) = f2b(fmaxf(v[3] * s4.w + h4.w, 0.f));
    }
  }
}

// ------------- fused local FU: ping-pong chunk staging, P1-B from global ----------
__global__ __launch_bounds__(256) void k_lfu(const unsigned short* __restrict__ DFTm,
                                             const unsigned short* __restrict__ lfuw,
                                             const unsigned short* __restrict__ IDFTm,
                                             const unsigned short* __restrict__ X1c,
                                             const float* __restrict__ scp,
                                             const float* __restrict__ shp,
                                             unsigned short* __restrict__ XSO) {
  __shared__ __align__(16) char SH[81920];
  char* M   = SH;
  char* S0  = SH + 16384;
  char* FFl = SH + 32768;
  char* Yl  = SH + 57344;
  int t = threadIdx.x, wid = t >> 6, l = t & 63, lr = l & 15, lg = l >> 4;
  int b = blockIdx.x; int n = b >> 6, h2 = b & 63;
  {
    #pragma unroll
    for (int i = 0; i < 3; i++) { int g = i * 256 + t; if (g < 640) gl16((const char*)DFTm + g * 16, M + g * 16); }
    #pragma unroll
    for (int i = 0; i < 4; i++) { int g = i * 256 + t; gl16((const char*)lfuw + g * 16, S0 + g * 16); }
    #pragma unroll
    for (int i = 0; i < 8; i++) {
      int u = i * 256 + t;
      if (u < 1920) *(unsigned*)(FFl + 33 * 512 + u * 4) = 0u;
    }
  }
  __syncthreads();
  {
    short8 bfp[2][2];
    #pragma unroll
    for (int nt = 0; nt < 2; nt++) {
      int c2 = wid * 32 + 16 * nt + lr;
      int c0 = c2 & 31, hb = (c2 >> 5) & 1, wbq = (c2 >> 6) & 1;
      int half = wbq ^ ((c0 >> 3) & 1);
      const char* base = (const char*)X1c +
          ((size_t)(n * 128 + hb * 64 + h2) * 128 + c0) * 256 + half * 128;
      #pragma unroll
      for (int ki = 0; ki < 2; ki++) {
        int kb = ki * 64 + lg * 16;
        bfp[nt][ki] = *(const short8*)(base + (kb ^ SW7b(c2)));
      }
    }
    f32x4 acc[5][2];
    #pragma unroll
    for (int mt = 0; mt < 5; mt++) { acc[mt][0] = (f32x4){0,0,0,0}; acc[mt][1] = (f32x4){0,0,0,0}; }
    #pragma unroll
    for (int ki = 0; ki < 2; ki++) {
      int kb = ki * 64 + lg * 16;
      #pragma unroll
      for (int mt = 0; mt < 5; mt++) {
        int m = 16 * mt + lr;
        short8 af = *(const short8*)(M + m * 128 + (kb ^ SW7b(m)));
        #pragma unroll
        for (int nt = 0; nt < 2; nt++)
          acc[mt][nt] = __builtin_amdgcn_mfma_f32_16x16x32_bf16(af, bfp[nt][ki], acc[mt][nt], 0, 0, 0);
      }
    }
    #pragma unroll
    for (int nt = 0; nt < 2; nt++) {
      int c2 = wid * 32 + 16 * nt + lr;
      #pragma unroll
      for (int mt = 0; mt < 5; mt++) {
        int rb = 16 * mt + lg * 4;
        int wf0 = rb >> 1;
        f32x4 v = acc[mt][nt];
        if (wf0 < 33) {
          unsigned pk = (unsigned)f2b(v[0]) | ((unsigned)f2b(v[1]) << 16);
          *(unsigned*)(FFl + wf0 * 512 + ((4 * c2) ^ SW7b(wf0))) = pk;
        }
        if (wf0 + 1 < 33) {
          unsigned pk = (unsigned)f2b(v[2]) | ((unsigned)f2b(v[3]) << 16);
          *(unsigned*)(FFl + (wf0 + 1) * 512 + ((4 * c2) ^ SW7b(wf0 + 1))) = pk;
        }
      }
    }
  }
  __syncthreads();
  int wm2 = wid >> 1, wn2 = wid & 1;
  for (int ch = 0; ch < 8; ch++) {
    char* Mc = (ch & 1) ? M : S0;
    char* Mn = (ch & 1) ? S0 : M;
    if (ch < 7) {
      #pragma unroll
      for (int i = 0; i < 4; i++) {
        int g = i * 256 + t;
        gl16((const char*)lfuw + (size_t)(ch + 1) * 16384 + g * 16, Mn + g * 16);
      }
    } else {
      #pragma unroll
      for (int i = 0; i < 3; i++) {
        int g = i * 256 + t;
        if (g < 768) gl16((const char*)IDFTm + g * 16, Mn + g * 16);
      }
    }
    int NT = wn2 ? 1 : 2;
    f32x4 acc[2];
    acc[0] = (f32x4){0,0,0,0}; acc[1] = (f32x4){0,0,0,0};
    int lm = wm2 * 16 + lr;
    for (int kk = 0; kk < 256; kk += 32) {
      int kb = kk * 2 + lg * 16;
      short8 af = *(const short8*)(Mc + lm * 512 + (kb ^ SW7b(lm)));
      #pragma unroll
      for (int j = 0; j < 2; j++) {
        if (j < NT) {
          int wf = wn2 * 32 + 16 * j + lr;
          short8 bf = *(const short8*)(FFl + wf * 512 + (kb ^ SW7b(wf)));
          acc[j] = __builtin_amdgcn_mfma_f32_16x16x32_bf16(af, bf, acc[j], 0, 0, 0);
        }
      }
    }
    int co = ch * 32 + wm2 * 16 + lg * 4;
    float4 s4 = *(const float4*)&scp[co];
    float4 h4 = *(const float4*)&shp[co];
    int cc0 = co >> 1;
    #pragma unroll
    for (int j = 0; j < 2; j++) {
      if (j < NT) {
        int wf = wn2 * 32 + 16 * j + lr;
        f32x4 v = acc[j];
        float v0 = fmaxf(v[0] * s4.x + h4.x, 0.f);
        float v1 = fmaxf(v[1] * s4.y + h4.y, 0.f);
        float v2 = fmaxf(v[2] * s4.z + h4.z, 0.f);
        float v3 = fmaxf(v[3] * s4.w + h4.w, 0.f);
        unsigned p0 = (unsigned)f2b(v0) | ((unsigned)f2b(v1) << 16);
        unsigned p1 = (unsigned)f2b(v2) | ((unsigned)f2b(v3) << 16);
        *(unsigned*)(Yl + (cc0 + 0) * 192 + ((4 * wf) ^ SW3b(cc0 + 0))) = p0;
        *(unsigned*)(Yl + (cc0 + 1) * 192 + ((4 * wf) ^ SW3b(cc0 + 1))) = p1;
      }
    }
    __syncthreads();
  }
  {
    f32x4 acc[8];
    #pragma unroll
    for (int nt = 0; nt < 8; nt++) acc[nt] = (f32x4){0,0,0,0};
    int w = wid * 16 + lr;
    for (int kk = 0; kk < 96; kk += 32) {
      int kb = kk * 2 + lg * 16;
      short8 af = *(const short8*)(S0 + w * 192 + (kb ^ SW3b(w)));
      #pragma unroll
      for (int nt = 0; nt < 8; nt++) {
        int cc = 16 * nt + lr;
        short8 bf = *(const short8*)(Yl + cc * 192 + (kb ^ SW3b(cc)));
        acc[nt] = __builtin_amdgcn_mfma_f32_16x16x32_bf16(af, bf, acc[nt], 0, 0, 0);
      }
    }
    int w0 = wid * 16 + lg * 4;
    #pragma unroll
    for (int nt = 0; nt < 8; nt++) {
      int cc = 16 * nt + lr;
      f32x4 v = acc[nt];
      ushort4 o;
      o.x = f2b(v[0]); o.y = f2b(v[1]); o.z = f2b(v[2]); o.w = f2b(v[3]);
      *(ushort4*)(XSO + (((size_t)n * 128 + cc) * 64 + h2) * 64 + w0) = o;
    }
  }
}

// ------------- fused FU + residual + conv2: 32x32x16; P1 bf2 prefetched -----------
__global__ __launch_bounds__(1024, 4) void k_fu(const unsigned short* __restrict__ DFTm,
                                                const unsigned short* __restrict__ fuw,
                                                const unsigned short* __restrict__ IDFTm,
                                                const unsigned short* __restrict__ w2m,
                                                const unsigned short* __restrict__ X1c,
                                                const unsigned short* __restrict__ XSO,
                                                const float* __restrict__ scF,
                                                const float* __restrict__ shF,
                                                float* __restrict__ out) {
  __shared__ __align__(16) char SH[161792];
  char* R0 = SH;               // 40KB: DFT -> fuw kc1 -> fuw kc3 -> w2 c1
  char* R1 = SH + 40960;       // 32KB: fuw kc0 -> fuw kc2 -> w2 c0
  char* R2 = SH + 73728;       // 48KB: FF[96][512B] (K15) -> IDFT[128][384B] (K7)
  char* R3 = SH + 122880;      // 38912B: Yb[128][304B] -> ACC[128][256B] (K15)
  int t = threadIdx.x, wid = t >> 6, l = t & 63;
  int lc = l & 31, hf = l >> 5;
  size_t nh = blockIdx.x;
  int n = (int)(nh >> 7), hh = (int)(nh & 127);
  const char* xb = (const char*)X1c + nh * 32768;

  #pragma unroll
  for (int i = 0; i < 3; i++) {
    int g = i * 1024 + t;
    if (g < 2560) gl16((const char*)DFTm + (size_t)g * 16, R0 + g * 16);
  }
  *(unsigned*)(R2 + 80 * 512 + t * 8) = 0u;
  *(unsigned*)(R2 + 80 * 512 + t * 8 + 4) = 0u;
  __syncthreads();
  // ---- P1: FF = DFT . X  (A=R0, B=global X1c prefetched). stage fuw kc0 -> R1 ----
  {
    #pragma unroll
    for (int i = 0; i < 2; i++) {
      int g = i * 1024 + t;
      gl16((const char*)fuw + (size_t)g * 16, R1 + g * 16);
    }
    int mb = wid & 3, nb = wid >> 2;
    int c = nb * 32 + lc;
    bool x2 = (wid < 4);
    int c2b = wid * 32 + lc;
    short8 bfp[8], bfp2[8];
    #pragma unroll
    for (int ks = 0; ks < 8; ks++)
      bfp[ks] = *(const short8*)(xb + (size_t)c * 256 + ((ks * 32 + hf * 16) ^ K15(c)));
    if (x2) {
      #pragma unroll
      for (int ks = 0; ks < 8; ks++)
        bfp2[ks] = *(const short8*)(xb + (size_t)c2b * 256 + ((ks * 32 + hf * 16) ^ K15(c2b)));
    }
    f32x16 acc0 = {0}, acc1 = {0};
    #pragma unroll
    for (int ks = 0; ks < 8; ks++) {
      int ko = ks * 32 + hf * 16;
      int m = mb * 32 + lc;
      short8 af = *(const short8*)(R0 + (size_t)m * 256 + (ko ^ K15(m)));
      acc0 = __builtin_amdgcn_mfma_f32_32x32x16_bf16(af, bfp[ks], acc0, 0, 0, 0);
      if (x2) {
        int m2 = 128 + lc;
        short8 af2 = *(const short8*)(R0 + (size_t)m2 * 256 + (ko ^ K15(m2)));
        acc1 = __builtin_amdgcn_mfma_f32_32x32x16_bf16(af2, bfp2[ks], acc1, 0, 0, 0);
      }
    }
    #pragma unroll
    for (int q = 0; q < 4; q++) {
      int wfe = mb * 16 + 4 * q + 2 * hf;
      unsigned p0 = pk2(acc0[4 * q + 0], acc0[4 * q + 1]);
      unsigned p1 = pk2(acc0[4 * q + 2], acc0[4 * q + 3]);
      *(unsigned*)(R2 + (size_t)wfe * 512 + ((4 * c) ^ K15(wfe))) = p0;
      *(unsigned*)(R2 + (size_t)(wfe + 1) * 512 + ((4 * c) ^ K15(wfe + 1))) = p1;
    }
    if (x2) {
      #pragma unroll
      for (int q = 0; q < 4; q++) {
        int wfe = 64 + 4 * q + 2 * hf;
        unsigned p0 = pk2(acc1[4 * q + 0], acc1[4 * q + 1]);
        unsigned p1 = pk2(acc1[4 * q + 2], acc1[4 * q + 3]);
        *(unsigned*)(R2 + (size_t)wfe * 512 + ((4 * c2b) ^ K15(wfe))) = p0;
        *(unsigned*)(R2 + (size_t)(wfe + 1) * 512 + ((4 * c2b) ^ K15(wfe + 1))) = p1;
      }
    }
  }
  // ---- P2: Y = ReLU(BN(fuw . FF)), K-sliced chunks, acc persists -----------------
  {
    int mb = wid >> 1, odd = wid & 1;
    int co = mb * 32 + lc;
    f32x16 pa = {0}, pb = {0};
    int wfA = (odd ? 32 : 0) + lc;
    int wfB = 64 + lc;
    #pragma unroll
    for (int ch = 0; ch < 4; ch++) {
      char* Mc = (ch & 1) ? R0 : R1;
      char* Mn = (ch & 1) ? R1 : R0;
      __syncthreads();
      if (ch < 3) {
        #pragma unroll
        for (int i = 0; i < 2; i++) {
          int g = i * 1024 + t;
          gl16((const char*)fuw + (size_t)(ch + 1) * 32768 + (size_t)g * 16, Mn + g * 16);
        }
      } else {
        #pragma unroll
        for (int i = 0; i < 2; i++) {
          int g = i * 1024 + t;
          gl16((const char*)w2m + (size_t)g * 16, Mn + g * 16);
        }
      }
      #pragma unroll
      for (int ks = 0; ks < 4; ks++) {
        int ko = ks * 32 + hf * 16;
        short8 af = *(const short8*)(Mc + (size_t)co * 128 + (ko ^ K7(co)));
        int kg = (ch * 4 + ks) * 32 + hf * 16;
        short8 bfA = *(const short8*)(R2 + (size_t)wfA * 512 + (kg ^ K15(wfA)));
        pa = __builtin_amdgcn_mfma_f32_32x32x16_bf16(af, bfA, pa, 0, 0, 0);
        if (!odd) {
          short8 bfB = *(const short8*)(R2 + (size_t)wfB * 512 + (kg ^ K15(wfB)));
          pb = __builtin_amdgcn_mfma_f32_32x32x16_bf16(af, bfB, pb, 0, 0, 0);
        }
      }
    }
    #pragma unroll
    for (int q = 0; q < 4; q++) {
      int co0 = mb * 32 + 8 * q + 4 * hf;
      float4 s4 = *(const float4*)&scF[co0];
      float4 h4 = *(const float4*)&shF[co0];
      int cc0 = co0 >> 1;
      {
        float v0 = fmaxf(pa[4 * q + 0] * s4.x + h4.x, 0.f);
        float v1 = fmaxf(pa[4 * q + 1] * s4.y + h4.y, 0.f);
        float v2 = fmaxf(pa[4 * q + 2] * s4.z + h4.z, 0.f);
        float v3 = fmaxf(pa[4 * q + 3] * s4.w + h4.w, 0.f);
        *(unsigned*)(R3 + (size_t)(cc0 + 0) * 304 + 4 * wfA) = pk2(v0, v1);
        *(unsigned*)(R3 + (size_t)(cc0 + 1) * 304 + 4 * wfA) = pk2(v2, v3);
      }
      if (!odd && lc < 12) {
        float v0 = fmaxf(pb[4 * q + 0] * s4.x + h4.x, 0.f);
        float v1 = fmaxf(pb[4 * q + 1] * s4.y + h4.y, 0.f);
        float v2 = fmaxf(pb[4 * q + 2] * s4.z + h4.z, 0.f);
        float v3 = fmaxf(pb[4 * q + 3] * s4.w + h4.w, 0.f);
        *(unsigned*)(R3 + (size_t)(cc0 + 0) * 304 + 4 * wfB) = pk2(v0, v1);
        *(unsigned*)(R3 + (size_t)(cc0 + 1) * 304 + 4 * wfB) = pk2(v2, v3);
      }
    }
  }
  __syncthreads();
  #pragma unroll
  for (int i = 0; i < 3; i++) {
    int g = i * 1024 + t;
    gl16((const char*)IDFTm + (size_t)g * 16, R2 + g * 16);
  }
  #pragma unroll
  for (int i = 0; i < 2; i++) {
    int g = i * 1024 + t;
    gl16((const char*)w2m + 32768 + (size_t)g * 16, R0 + g * 16);
  }
  __syncthreads();
  // ---- P3: ACC = IDFT . Y + x1 + xs (A=R2 384B K7, B=R3 304B) --------------------
  {
    int mb = wid & 3, nb = wid >> 2;
    int mw = mb * 32 + lc;
    int cc = nb * 32 + lc;
    ushort4 rx[4], rs[4];
    #pragma unroll
    for (int q = 0; q < 4; q++) {
      int w0 = mb * 32 + 8 * q + 4 * hf;
      rx[q] = *(const ushort4*)(xb + (size_t)cc * 256 + ((2 * w0) ^ K15(cc)));
      rs[q] = *(const ushort4*)(XSO + (((size_t)n * 128 + cc) * 64 + (hh & 63)) * 64 + (w0 & 63));
    }
    f32x16 p3 = {0};
    #pragma unroll
    for (int ks = 0; ks < 9; ks++) {
      int ko = ks * 32 + hf * 16;
      short8 af = *(const short8*)(R2 + (size_t)mw * 384 + (ko ^ K7(mw)));
      short8 bf = *(const short8*)(R3 + (size_t)cc * 304 + ko);
      p3 = __builtin_amdgcn_mfma_f32_32x32x16_bf16(af, bf, p3, 0, 0, 0);
    }
    __syncthreads();
    #pragma unroll
    for (int q = 0; q < 4; q++) {
      int w0 = mb * 32 + 8 * q + 4 * hf;
      float f0 = p3[4 * q + 0] + b2f(rx[q].x) + b2f(rs[q].x);
      float f1 = p3[4 * q + 1] + b2f(rx[q].y) + b2f(rs[q].y);
      float f2_ = p3[4 * q + 2] + b2f(rx[q].z) + b2f(rs[q].z);
      float f3 = p3[4 * q + 3] + b2f(rx[q].w) + b2f(rs[q].w);
      *(unsigned short*)(R3 + (size_t)(w0 + 0) * 256 + ((2 * cc) ^ K15(w0 + 0))) = f2b(f0);
      *(unsigned short*)(R3 + (size_t)(w0 + 1) * 256 + ((2 * cc) ^ K15(w0 + 1))) = f2b(f1);
      *(unsigned short*)(R3 + (size_t)(w0 + 2) * 256 + ((2 * cc) ^ K15(w0 + 2))) = f2b(f2_);
      *(unsigned short*)(R3 + (size_t)(w0 + 3) * 256 + ((2 * cc) ^ K15(w0 + 3))) = f2b(f3);
    }
  }
  __syncthreads();
  // ---- P4: out = (ACC . w2^T), m=w, n=co2 -> coalesced scalar stores -------------
  {
    int mb = wid & 3, nb = wid >> 2;
    int mw = mb * 32 + lc;
    int rco = nb * 32 + lc;
    #pragma unroll
    for (int ck = 0; ck < 2; ck++) {
      const char* Mc = ck ? R0 : R1;
      f32x16 p4 = {0};
      #pragma unroll
      for (int ks = 0; ks < 8; ks++) {
        int ko = ks * 32 + hf * 16;
        short8 af = *(const short8*)(R3 + (size_t)mw * 256 + (ko ^ K15(mw)));
        short8 bf = *(const short8*)(Mc + (size_t)rco * 256 + (ko ^ K15(rco)));
        p4 = __builtin_amdgcn_mfma_f32_32x32x16_bf16(af, bf, p4, 0, 0, 0);
      }
      float* obase = out + (nh * 128 + mb * 32) * 256 + ck * 128 + nb * 32 + lc;
      #pragma unroll
      for (int q = 0; q < 4; q++) {
        #pragma unroll
        for (int i = 0; i < 4; i++) {
          int wrow = 8 * q + 4 * hf + i;
          obase[(size_t)wrow * 256] = p4[4 * q + i];
        }
      }
    }
  }
}

extern "C" void kernel_launch(void* const* d_in, const int* in_sizes, int n_in,
                              void* d_out, int out_size, void* d_ws, size_t ws_size,
                              hipStream_t stream) {
  const float* x     = (const float*)d_in[0];
  const float* w1    = (const float*)d_in[1];
  const float* g1    = (const float*)d_in[2];
  const float* b1    = (const float*)d_in[3];
  const float* m1    = (const float*)d_in[4];
  const float* v1    = (const float*)d_in[5];
  const float* fu_w  = (const float*)d_in[6];
  const float* fu_g  = (const float*)d_in[7];
  const float* fu_b  = (const float*)d_in[8];
  const float* fu_m  = (const float*)d_in[9];
  const float* fu_v  = (const float*)d_in[10];
  const float* lfu_w = (const float*)d_in[11];
  const float* lfu_g = (const float*)d_in[12];
  const float* lfu_b = (const float*)d_in[13];
  const float* lfu_m = (const float*)d_in[14];
  const float* lfu_v = (const float*)d_in[15];
  const float* w2    = (const float*)d_in[16];
  float* out = (float*)d_out;

  char* p = (char*)d_ws;
  unsigned short* X1c = (unsigned short*)p; p += 33554432;   // [nh][c][w] bf16, K15 rows
  unsigned short* XSO = (unsigned short*)p; p += 8388608;    // [n][cc][h2][w2] bf16
  unsigned short* w1b   = (unsigned short*)p; p += 65536;
  unsigned short* fuwb  = (unsigned short*)p; p += 131072;   // k-sliced
  unsigned short* lfuwb = (unsigned short*)p; p += 131072;
  unsigned short* w2b   = (unsigned short*)p; p += 65536;
  unsigned short* DFTf  = (unsigned short*)p; p += 40960;    // [160][128]
  unsigned short* IDFTf = (unsigned short*)p; p += 49152;    // [128][192]
  unsigned short* DFTl  = (unsigned short*)p; p += 10240;
  unsigned short* IDFTl = (unsigned short*)p; p += 12288;
  float* sc1 = (float*)p; p += 512;
  float* sh1 = (float*)p; p += 512;
  float* scF = (float*)p; p += 1024;
  float* shF = (float*)p; p += 1024;
  float* scL = (float*)p; p += 1024;
  float* shL = (float*)p; p += 1024;

  k_wt<<<dim3(256), dim3(256), 0, stream>>>(w1, fu_w, lfu_w, w2, g1, b1, m1, v1,
                                            fu_g, fu_b, fu_m, fu_v, lfu_g, lfu_b, lfu_m, lfu_v,
                                            w1b, fuwb, lfuwb, w2b, DFTf, IDFTf, DFTl, IDFTl,
                                            sc1, sh1, scF, shF, scL, shL);
  k_conv1<<<dim3(512), dim3(512), 0, stream>>>(w1b, x, X1c, sc1, sh1);
  k_lfu<<<dim3(512), dim3(256), 0, stream>>>(DFTl, lfuwb, IDFTl, X1c, scL, shL, XSO);
  k_fu<<<dim3(1024), dim3(1024), 0, stream>>>(DFTf, fuwb, IDFTf, w2b, X1c, XSO, scF, shF, out);
}